// Round 10
// baseline (47.020 us; speedup 1.0000x reference)
//
#include <hip/hip_runtime.h>
#include <math.h>

// Problem constants (from reference)
#define NUM_T   8      // NUM_NODE_TYPES
#define TIN     16     // 2 * NUM_NODE_TYPES
#define HID     64     // HIDDEN
#define OUTD    16     // D*D
#define LN_EPS  1e-5f

#define N_PACK_U32  12500   // ceil(100000 / 8) ; 12500 % 4 == 0
#define PACK_BLOCKS 49      // ceil(12500 / 256)

typedef float f32x4 __attribute__((ext_vector_type(4)));

// ---------------------------------------------------------------------------
// k0: blocks [0,49): pack node types to nibbles (8 per u32).
//     blocks [49,113): one (ts,tt) pair per block; one wave computes the
//     16-float output row straight from L2 (coalesced, no LDS).
// ws: [0,4KB) table ; [4KB,54KB) packed nibbles.
// ---------------------------------------------------------------------------
__global__ __launch_bounds__(256) void
prep_kernel(const int* __restrict__ ntypes, int n_nodes,
            const float* __restrict__ ln_g,
            const float* __restrict__ ln_b,
            const float* __restrict__ W1,   // [16][64]
            const float* __restrict__ b1,   // [64]
            const float* __restrict__ W2,   // [64][16]
            const float* __restrict__ b2,   // [16]
            f32x4* __restrict__ table4,     // [64][4]
            unsigned int* __restrict__ packed)
{
    const int t = threadIdx.x;

    if (blockIdx.x < PACK_BLOCKS) {
        const int g = blockIdx.x * 256 + t;
        if (g < N_PACK_U32) {
            unsigned int w = 0;
            int n0 = g * 8;
            #pragma unroll
            for (int j = 0; j < 8; ++j) {
                int n = n0 + j;
                unsigned int ty = (n < n_nodes) ? (unsigned int)ntypes[n] : 0u;
                w |= (ty & 7u) << (j * 4);
            }
            packed[g] = w;
        }
        return;
    }

    // ---- table build: one pair per block, lanes 0..63 = k ----
    if (t >= 64) return;
    const int p  = blockIdx.x - PACK_BLOCKS;   // 0..63
    const int ts = p >> 3;
    const int tt = p & 7;
    const int k  = t;

    const float mu = 2.0f / 16.0f;
    float var = 0.0f;
    #pragma unroll
    for (int j = 0; j < TIN; ++j) {
        float h = (j == ts || j == (8 + tt)) ? 1.0f : 0.0f;
        float d = h - mu;
        var += d * d;
    }
    var *= (1.0f / 16.0f);
    const float inv = rsqrtf(var + LN_EPS);

    float a = b1[k];
    #pragma unroll
    for (int j = 0; j < TIN; ++j) {
        float h  = (j == ts || j == (8 + tt)) ? 1.0f : 0.0f;
        float hn = (h - mu) * inv * ln_g[j] + ln_b[j];
        a += hn * W1[j * HID + k];
    }
    a = fmaxf(a, 0.0f);

    const f32x4* W2v = (const f32x4*)W2;   // [64][4]
    f32x4 w0 = W2v[k * 4 + 0], w1 = W2v[k * 4 + 1],
          w2 = W2v[k * 4 + 2], w3 = W2v[k * 4 + 3];

    float s[OUTD];
    #pragma unroll
    for (int i = 0; i < 4; ++i) {
        s[0 + i]  = a * w0[i];
        s[4 + i]  = a * w1[i];
        s[8 + i]  = a * w2[i];
        s[12 + i] = a * w3[i];
    }
    #pragma unroll
    for (int o = 0; o < OUTD; ++o) {
        s[o] += __shfl_xor(s[o], 1);
        s[o] += __shfl_xor(s[o], 2);
        s[o] += __shfl_xor(s[o], 4);
        s[o] += __shfl_xor(s[o], 8);
        s[o] += __shfl_xor(s[o], 16);
        s[o] += __shfl_xor(s[o], 32);
        s[o] += b2[o];
    }

    if (t < 4) {
        const int r = t;
        float s0 = s[4*r+0], s1 = s[4*r+1], s2 = s[4*r+2], s3 = s[4*r+3];
        float m  = fmaxf(fmaxf(s0, s1), fmaxf(s2, s3));
        float e0 = expf(s0 - m), e1 = expf(s1 - m),
              e2 = expf(s2 - m), e3 = expf(s3 - m);
        float rs = 1.0f / (e0 + e1 + e2 + e3);
        f32x4 outv;
        outv.x = (r == 0 ? 1.0f : 0.0f) - e0 * rs;
        outv.y = (r == 1 ? 1.0f : 0.0f) - e1 * rs;
        outv.z = (r == 2 ? 1.0f : 0.0f) - e2 * rs;
        outv.w = (r == 3 ? 1.0f : 0.0f) - e3 * rs;
        table4[p * 4 + r] = outv;
    }
}

// ---------------------------------------------------------------------------
// k1 (EXACT path, E % 256 == 0): 256-edge chunks per wave-iteration.
//   - int4 index loads: 4 edges/lane, 2 coalesced dwordx4 loads per chunk
//   - pack 4 pair-ids into one u32 per lane
//   - 16 independent fully-coalesced 1 KB wave stores per chunk
//     (shfl-byte-extract + ds_read_b128 each; nothing cross-dependent)
//   -> 16 KB of stores in flight per wave vs 4 KB in the R8 version.
// 1-deep prefetch of the next chunk's indices hides HBM load latency.
// ---------------------------------------------------------------------------
__global__ __launch_bounds__(1024) void
scatter_edges_exact(const int* __restrict__ row,
                    const int* __restrict__ col,
                    const unsigned int* __restrict__ packed, // [N_PACK_U32]
                    const f32x4* __restrict__ table4,        // [64][4]
                    f32x4* __restrict__ out4,                // [E][4]
                    int nchunks)                             // E / 256
{
    __shared__ f32x4 lds_table[64 * 5];              // stride-5 pad (bank fix)
    __shared__ unsigned int nt_lds[N_PACK_U32];      // 50 KB packed nibbles

    const int t = threadIdx.x;

    if (t < 256) {   // stage table (5 KB)
        int p = t >> 2, q = t & 3;
        lds_table[p * 5 + q] = table4[t];
    }
    {   // stage packed types (50 KB); 12500/4 = 3125 exact
        const uint4* s4 = (const uint4*)packed;
        uint4* d4 = (uint4*)nt_lds;
        for (int i = t; i < N_PACK_U32 / 4; i += 1024) d4[i] = s4[i];
    }
    __syncthreads();

    const int lane = t & 63;
    const int wid  = t >> 6;            // wave in block, 0..15
    const int q        = lane & 3;      // output quad
    const int selshift = 8 * ((lane >> 2) & 3);
    const int lhi      = lane >> 4;     // 0..3

    const int4* row4 = (const int4*)row;
    const int4* col4 = (const int4*)col;

    int ci = blockIdx.x * 16 + wid;     // chunk index
    const int stride = gridDim.x * 16;
    if (ci >= nchunks) return;

    // prologue: indices for the first chunk (4 edges per lane)
    int4 rv = row4[ci * 64 + lane];
    int4 cv = col4[ci * 64 + lane];

    while (true) {
        const int nci = ci + stride;
        const bool have_next = (nci < nchunks);

        // top: prefetch next chunk's indices
        int4 rvn, cvn;
        if (have_next) {
            rvn = row4[nci * 64 + lane];
            cvn = col4[nci * 64 + lane];
        }

        // pair ids for this lane's 4 edges, packed into one u32
        unsigned int pp = 0;
        {
            int rr[4] = {rv.x, rv.y, rv.z, rv.w};
            int cc[4] = {cv.x, cv.y, cv.z, cv.w};
            #pragma unroll
            for (int j = 0; j < 4; ++j) {
                unsigned int tr = (nt_lds[rr[j] >> 3] >> ((rr[j] & 7) * 4)) & 7u;
                unsigned int tc = (nt_lds[cc[j] >> 3] >> ((cc[j] & 7) * 4)) & 7u;
                pp |= ((tr << 3) | tc) << (8 * j);
            }
        }

        // 16 independent 1 KB wave stores.
        // Store i, lane l covers edge ci*256 + i*16 + (l>>2), quad l&3:
        // out4 index = ci*1024 + i*64 + l (contiguous across the wave).
        const int base4 = ci * 1024;
        #pragma unroll
        for (int i = 0; i < 16; ++i) {
            unsigned int ppj = (unsigned int)__shfl((int)pp, 4 * i + lhi, 64);
            int pj = (int)((ppj >> selshift) & 63u);
            out4[base4 + i * 64 + lane] = lds_table[pj * 5 + q];
        }

        if (!have_next) break;
        ci = nci;
        rv = rvn;
        cv = cvn;
    }
}

// ---------------------------------------------------------------------------
// Generic fallback (any E): R8's 64-edge pipelined kernel.
// ---------------------------------------------------------------------------
__global__ __launch_bounds__(1024) void
scatter_edges_generic(const int* __restrict__ row,
                      const int* __restrict__ col,
                      const unsigned int* __restrict__ packed,
                      const f32x4* __restrict__ table4,
                      f32x4* __restrict__ out4,
                      int E)
{
    __shared__ f32x4 lds_table[64 * 5];
    __shared__ unsigned int nt_lds[N_PACK_U32];

    const int t = threadIdx.x;

    if (t < 256) {
        int p = t >> 2, q = t & 3;
        lds_table[p * 5 + q] = table4[t];
    }
    {
        const uint4* s4 = (const uint4*)packed;
        uint4* d4 = (uint4*)nt_lds;
        for (int i = t; i < N_PACK_U32 / 4; i += 1024) d4[i] = s4[i];
    }
    __syncthreads();

    const int lane = t & 63;
    const int wid  = t >> 6;
    const int q    = lane & 3;
    const int sub  = lane >> 2;
    const int stride = gridDim.x * 1024;

    for (int base = blockIdx.x * 1024 + wid * 64; base < E; base += stride) {
        int e  = base + lane;
        int ec = (e < E) ? e : (E - 1);
        int r = row[ec];
        int c = col[ec];
        unsigned int tr = (nt_lds[r >> 3] >> ((r & 7) * 4)) & 7u;
        unsigned int tc = (nt_lds[c >> 3] >> ((c & 7) * 4)) & 7u;
        int pair = (int)((tr << 3) | tc);

        #pragma unroll
        for (int j = 0; j < 4; ++j) {
            int src = j * 16 + sub;
            int pj  = __shfl(pair, src, 64);
            int ej  = base + src;
            if (ej < E) out4[ej * 4 + q] = lds_table[pj * 5 + q];
        }
    }
}

// ---------------------------------------------------------------------------
extern "C" void kernel_launch(void* const* d_in, const int* in_sizes, int n_in,
                              void* d_out, int out_size, void* d_ws, size_t ws_size,
                              hipStream_t stream)
{
    // Inputs: x, edge_index, node_types, ln_g, ln_b, W1, b1, W2, b2
    const int*   edge_index = (const int*)d_in[1];   // [2][E] int32
    const int*   ntypes     = (const int*)d_in[2];   // [N] int32
    const float* ln_g       = (const float*)d_in[3];
    const float* ln_b       = (const float*)d_in[4];
    const float* W1         = (const float*)d_in[5];
    const float* b1         = (const float*)d_in[6];
    const float* W2         = (const float*)d_in[7];
    const float* b2         = (const float*)d_in[8];

    const int E = in_sizes[1] / 2;
    const int N = in_sizes[2];

    f32x4*        table4 = (f32x4*)d_ws;                        // 4 KB
    unsigned int* packed = (unsigned int*)((char*)d_ws + 4096); // 50 KB

    prep_kernel<<<PACK_BLOCKS + 64, 256, 0, stream>>>(
        ntypes, N, ln_g, ln_b, W1, b1, W2, b2, table4, packed);

    if ((E & 255) == 0) {
        // 1 block/CU, 16 waves/CU; 12500 chunks over 4096 waves (~3 iters)
        scatter_edges_exact<<<256, 1024, 0, stream>>>(
            edge_index, edge_index + E, packed, table4, (f32x4*)d_out, E >> 8);
    } else {
        scatter_edges_generic<<<512, 1024, 0, stream>>>(
            edge_index, edge_index + E, packed, table4, (f32x4*)d_out, E);
    }
}